// Round 1
// baseline (2142.173 us; speedup 1.0000x reference)
//
#include <hip/hip_runtime.h>
#include <hip/hip_bf16.h>

#define T_LEN 4096

typedef __attribute__((ext_vector_type(8))) short bfrag8;
typedef __attribute__((ext_vector_type(4))) float f32x4;

// Workgroup barrier WITHOUT vmcnt(0) drain: keeps global prefetch loads in
// flight across the barrier (the __syncthreads() lowering would drain them).
__device__ __forceinline__ void wg_barrier() {
  asm volatile("s_waitcnt lgkmcnt(0)\ns_barrier" ::: "memory");
}

__device__ __forceinline__ float fsigmoid(float x) {
  float e = __builtin_amdgcn_exp2f(-1.4426950408889634f * x);
  return __builtin_amdgcn_rcpf(1.0f + e);
}
__device__ __forceinline__ float ftanh(float x) {
  float e = __builtin_amdgcn_exp2f(2.8853900817779268f * x);  // exp(2x)
  return 1.0f - 2.0f * __builtin_amdgcn_rcpf(1.0f + e);
}

// ---------------------------------------------------------------------------
// Kernel 1: build fused weights.
//   Wc[dir][n][k] (bf16, K=128): k in [0,60)  = sum_e W_ih[n][e]*W_enc[e][k]
//                                k in [60,64) = 0 (pad)
//                                k in [64,128)= W_hh[n][k-64]
//   biasc[dir][n] = b[n] + sum_e W_ih[n][e]*b_enc[e]   (fp32)
// ---------------------------------------------------------------------------
__global__ void prep_weights(const float* __restrict__ W_enc,
                             const float* __restrict__ b_enc,
                             const float* __restrict__ W_ih_f,
                             const float* __restrict__ W_hh_f,
                             const float* __restrict__ b_f,
                             const float* __restrict__ W_ih_b,
                             const float* __restrict__ W_hh_b,
                             const float* __restrict__ b_b,
                             __hip_bfloat16* __restrict__ Wc,
                             float* __restrict__ biasc) {
  const int dir = blockIdx.x;     // 0 = fwd, 1 = bwd
  const int n = threadIdx.x;      // 0..255 gate row
  const float* W_ih = dir ? W_ih_b : W_ih_f;
  const float* W_hh = dir ? W_hh_b : W_hh_f;
  const float* bv   = dir ? b_b   : b_f;

  float wi[32];
#pragma unroll
  for (int e = 0; e < 32; ++e) wi[e] = W_ih[n * 32 + e];

  __hip_bfloat16* wrow = Wc + ((size_t)dir * 256 + n) * 128;
  for (int k = 0; k < 60; ++k) {
    float v = 0.0f;
#pragma unroll
    for (int e = 0; e < 32; ++e) v += wi[e] * W_enc[e * 60 + k];
    wrow[k] = __float2bfloat16(v);
  }
#pragma unroll
  for (int k = 60; k < 64; ++k) wrow[k] = __float2bfloat16(0.0f);
  for (int k = 0; k < 64; ++k) wrow[64 + k] = __float2bfloat16(W_hh[n * 64 + k]);

  float bb = bv[n];
#pragma unroll
  for (int e = 0; e < 32; ++e) bb += wi[e] * b_enc[e];
  biasc[dir * 256 + n] = bb;
}

// ---------------------------------------------------------------------------
// Kernel 2: the sequential bidirectional LSTM.
// Grid: 128 WGs = 64 batch-tiles(4) x 2 directions. Block: 512 threads (8 waves).
// Waves 0-7: MFMA gates = A[16,128] @ Wc^T (2 N-tiles each, W frags in regs).
// Waves 0-3: cell update (1 thread = 1 (batch,unit), c-state in a VGPR).
// Waves 4-7: stage c-features for t+1 into LDS + depth-4 global prefetch.
// A LDS layout: 4 rows x 144 bf16, cols [0,60)=c-feats, [60,64)=0, [64,128)=h.
// Stride 144 -> bank group 4*(2r+q) mod 32: perfect 2-way (free) on b128 reads.
// ---------------------------------------------------------------------------
__global__ __launch_bounds__(512) void lstm_main(
    const float* __restrict__ cin, const __hip_bfloat16* __restrict__ Wc,
    const float* __restrict__ biasc, float* __restrict__ cfin) {
  __shared__ short Abuf[4 * 144];
  __shared__ float gbuf[4 * 257];   // gates, row stride 257 breaks conflicts

  const int tid  = threadIdx.x;
  const int lane = tid & 63;
  const int wave = tid >> 6;
  const int quad = lane >> 4;
  const int wg   = blockIdx.x;
  const int dir  = wg >> 6;
  const int b0   = (wg & 63) << 2;

  // ---- loop-invariant W fragments into registers (B-operand layout:
  // lane holds B[k=quad*8+j][n=lane&15] = W[n][k], j contiguous) ----
  const int l15 = lane & 15;
  const int n0 = wave * 32 + l15;       // N-tile 2*wave
  const int n1 = n0 + 16;               // N-tile 2*wave+1
  const __hip_bfloat16* wrow0 = Wc + ((size_t)(dir * 256 + n0)) * 128 + quad * 8;
  const __hip_bfloat16* wrow1 = Wc + ((size_t)(dir * 256 + n1)) * 128 + quad * 8;
  bfrag8 wf0[4], wf1[4];
#pragma unroll
  for (int kt = 0; kt < 4; ++kt) {
    wf0[kt] = *(const bfrag8*)(wrow0 + kt * 32);
    wf1[kt] = *(const bfrag8*)(wrow1 + kt * 32);
  }
  const float bias0 = biasc[dir * 256 + n0];  // folded into acc init (C/D col = lane&15)
  const float bias1 = biasc[dir * 256 + n1];

  __hip_bfloat16* Ab = (__hip_bfloat16*)Abuf;
  const int ub = tid >> 6;    // update: batch row   (valid when tid < 256)
  const int uu = tid & 63;    // update: hidden unit
  float cstate = 0.0f;

  const int sr = (tid >> 6) - 4;   // staging: batch row (waves 4-7)
  const float* cr = cin;
  int l60 = 0;
  float vbuf[4] = {0.f, 0.f, 0.f, 0.f};

  if (tid < 256) {
    Ab[ub * 144 + 64 + uu] = __float2bfloat16(0.0f);          // h0 = 0
    if (uu < 4) Ab[ub * 144 + 60 + uu] = __float2bfloat16(0.0f);  // K pad
  } else {
    cr  = cin + (size_t)(b0 + sr) * T_LEN * 60;
    l60 = (lane < 60) ? lane : 59;
    int tp0 = dir ? (T_LEN - 1) : 0;
    float v0 = cr[(size_t)tp0 * 60 + l60];                    // stage t=0 now
    if (lane < 60) Ab[sr * 144 + lane] = __float2bfloat16(v0);
#pragma unroll
    for (int q = 1; q <= 4; ++q) {                            // prefetch t=1..4
      int tp = dir ? (T_LEN - 1 - q) : q;
      vbuf[q & 3] = cr[(size_t)tp * 60 + l60];
    }
  }
  wg_barrier();

#pragma unroll 4
  for (int t = 0; t < T_LEN; ++t) {
    // ---- phase M: gates = A @ W^T (+bias via acc init), all 8 waves ----
    // A-operand row = lane&15; only rows 0-3 valid -> read row lane&3 so
    // rows 4-15 are same-address broadcasts (free, no extra LDS BW).
    const short* arow = Abuf + (lane & 3) * 144 + quad * 8;
    bfrag8 af0 = *(const bfrag8*)(arow);
    bfrag8 af1 = *(const bfrag8*)(arow + 32);
    bfrag8 af2 = *(const bfrag8*)(arow + 64);
    bfrag8 af3 = *(const bfrag8*)(arow + 96);
    f32x4 acc0 = {bias0, bias0, bias0, bias0};
    f32x4 acc1 = {bias1, bias1, bias1, bias1};
    acc0 = __builtin_amdgcn_mfma_f32_16x16x32_bf16(af0, wf0[0], acc0, 0, 0, 0);
    acc1 = __builtin_amdgcn_mfma_f32_16x16x32_bf16(af0, wf1[0], acc1, 0, 0, 0);
    acc0 = __builtin_amdgcn_mfma_f32_16x16x32_bf16(af1, wf0[1], acc0, 0, 0, 0);
    acc1 = __builtin_amdgcn_mfma_f32_16x16x32_bf16(af1, wf1[1], acc1, 0, 0, 0);
    acc0 = __builtin_amdgcn_mfma_f32_16x16x32_bf16(af2, wf0[2], acc0, 0, 0, 0);
    acc1 = __builtin_amdgcn_mfma_f32_16x16x32_bf16(af2, wf1[2], acc1, 0, 0, 0);
    acc0 = __builtin_amdgcn_mfma_f32_16x16x32_bf16(af3, wf0[3], acc0, 0, 0, 0);
    acc1 = __builtin_amdgcn_mfma_f32_16x16x32_bf16(af3, wf1[3], acc1, 0, 0, 0);
    if (quad == 0) {  // C/D: col = lane&15, row = reg (quad 0 -> rows 0-3)
#pragma unroll
      for (int r = 0; r < 4; ++r) {
        gbuf[r * 257 + wave * 32 + lane]      = acc0[r];
        gbuf[r * 257 + wave * 32 + 16 + lane] = acc1[r];
      }
    }
    wg_barrier();

    // ---- phase U (waves 0-3): cell update ---- / phase S (waves 4-7) ----
    if (tid < 256) {
      const float* g = gbuf + ub * 257 + uu;
      float gi = g[0], gf = g[64], gg = g[128], go = g[192];  // i,f,g,o order
      float fi = fsigmoid(gi);
      float ff = fsigmoid(gf);
      float fo = fsigmoid(go);
      float fg = ftanh(gg);
      cstate = ff * cstate + fi * fg;
      float h = fo * ftanh(cstate);
      Ab[ub * 144 + 64 + uu] = __float2bfloat16(h);
    } else {
      float v = vbuf[(t + 1) & 3];                       // c(t+1), loaded t-3
      if (lane < 60) Ab[sr * 144 + lane] = __float2bfloat16(v);
      int tn = t + 5; tn = (tn > T_LEN - 1) ? (T_LEN - 1) : tn;  // clamp tail
      int tp = dir ? (T_LEN - 1 - tn) : tn;
      vbuf[(t + 1) & 3] = cr[(size_t)tp * 60 + l60];     // prefetch c(t+5)
    }
    wg_barrier();
  }

  if (tid < 256) {  // reference quirk: final CELL state feeds the FC
    cfin[((size_t)dir * 256 + b0 + ub) * 64 + uu] = cstate;
  }
}

// ---------------------------------------------------------------------------
// Kernel 3: out[b,:] = [c_fwd(b) ; c_bwd(b)] @ W_fin^T + b_fin
// ---------------------------------------------------------------------------
__global__ void final_fc(const float* __restrict__ cfin,
                         const float* __restrict__ W_fin,
                         const float* __restrict__ b_fin,
                         float* __restrict__ out) {
  int b = threadIdx.x;  // 256 threads, 1 block
  const float* cf = cfin + (size_t)b * 64;
  const float* cb = cfin + (size_t)(256 + b) * 64;
  float a0 = b_fin[0], a1 = b_fin[1], a2 = b_fin[2];
  for (int u = 0; u < 64; ++u) {
    float vf = cf[u], vb = cb[u];
    a0 += W_fin[0 * 128 + u] * vf + W_fin[0 * 128 + 64 + u] * vb;
    a1 += W_fin[1 * 128 + u] * vf + W_fin[1 * 128 + 64 + u] * vb;
    a2 += W_fin[2 * 128 + u] * vf + W_fin[2 * 128 + 64 + u] * vb;
  }
  out[b * 3 + 0] = a0;
  out[b * 3 + 1] = a1;
  out[b * 3 + 2] = a2;
}

extern "C" void kernel_launch(void* const* d_in, const int* in_sizes, int n_in,
                              void* d_out, int out_size, void* d_ws, size_t ws_size,
                              hipStream_t stream) {
  (void)in_sizes; (void)n_in; (void)out_size; (void)ws_size;
  const float* c      = (const float*)d_in[0];
  const float* W_enc  = (const float*)d_in[1];
  const float* b_enc  = (const float*)d_in[2];
  const float* W_ih_f = (const float*)d_in[3];
  const float* W_hh_f = (const float*)d_in[4];
  const float* b_f    = (const float*)d_in[5];
  const float* W_ih_b = (const float*)d_in[6];
  const float* W_hh_b = (const float*)d_in[7];
  const float* b_b    = (const float*)d_in[8];
  const float* W_fin  = (const float*)d_in[9];
  const float* b_fin  = (const float*)d_in[10];
  float* out = (float*)d_out;

  char* ws = (char*)d_ws;
  __hip_bfloat16* Wc = (__hip_bfloat16*)ws;           // 2*256*128*2 = 131072 B
  float* biasc = (float*)(ws + 131072);               // 2*256*4    = 2048 B
  float* cfin  = (float*)(ws + 131072 + 2048);        // 2*256*64*4 = 131072 B

  prep_weights<<<2, 256, 0, stream>>>(W_enc, b_enc, W_ih_f, W_hh_f, b_f,
                                      W_ih_b, W_hh_b, b_b, Wc, biasc);
  lstm_main<<<128, 512, 0, stream>>>(c, Wc, biasc, cfin);
  final_fc<<<1, 256, 0, stream>>>(cfin, W_fin, b_fin, out);
}

// Round 2
// 2040.316 us; speedup vs baseline: 1.0499x; 1.0499x over previous
//
#include <hip/hip_runtime.h>
#include <hip/hip_bf16.h>

#define T_LEN 4096

typedef __attribute__((ext_vector_type(8))) short bfrag8;
typedef __attribute__((ext_vector_type(4))) float f32x4;

// Workgroup barrier WITHOUT vmcnt(0) drain: keeps global prefetch loads in
// flight across the barrier (the __syncthreads() lowering would drain them).
__device__ __forceinline__ void wg_barrier() {
  asm volatile("s_waitcnt lgkmcnt(0)\ns_barrier" ::: "memory");
}

__device__ __forceinline__ float fact(float x, float S, float A, float B) {
  // sigmoid: S=-1/ln2, A=0, B=1 ;  tanh: S=+2/ln2, A=1, B=-2
  float e = __builtin_amdgcn_exp2f(S * x);
  return A + B * __builtin_amdgcn_rcpf(1.0f + e);
}
__device__ __forceinline__ float ftanh(float x) {
  float e = __builtin_amdgcn_exp2f(2.8853900817779268f * x);
  return 1.0f - 2.0f * __builtin_amdgcn_rcpf(1.0f + e);
}
// Broadcast lane SEL within each aligned 4-lane group (quad_perm DPP, VALU).
template <int SEL>
__device__ __forceinline__ float qb(float v) {
  union { float f; int i; } u;
  u.f = v;
  u.i = __builtin_amdgcn_mov_dpp(u.i, SEL * 0x55, 0xF, 0xF, true);
  return u.f;
}

// ---------------------------------------------------------------------------
// Kernel 1: encoder  x[b*T+t][u] = sum_k c[..][k] * W_enc[u][k]  (bf16 out).
// b_enc is NOT added here; it is folded (fp32) into the LSTM bias.
// Memory-bound: reads 251 MB fp32, writes 64 MB bf16.
// ---------------------------------------------------------------------------
__global__ __launch_bounds__(256) void encoder(const float* __restrict__ c,
                                               const float* __restrict__ W_enc,
                                               __hip_bfloat16* __restrict__ x) {
  const int u = threadIdx.x & 31;     // encoder output unit
  const int rs = threadIdx.x >> 5;    // row slot (8 rows each)
  const size_t row0 = (size_t)blockIdx.x * 64 + (size_t)rs * 8;
  float4 wq[15];
#pragma unroll
  for (int i = 0; i < 15; ++i) wq[i] = *(const float4*)(W_enc + u * 60 + i * 4);
#pragma unroll
  for (int r = 0; r < 8; ++r) {
    const float* cr = c + (row0 + r) * 60;
    float acc = 0.f;
#pragma unroll
    for (int i = 0; i < 15; ++i) {
      float4 cv = *(const float4*)(cr + i * 4);
      acc += cv.x * wq[i].x;
      acc += cv.y * wq[i].y;
      acc += cv.z * wq[i].z;
      acc += cv.w * wq[i].w;
    }
    x[(row0 + r) * 32 + u] = __float2bfloat16(acc);
  }
}

// ---------------------------------------------------------------------------
// Kernel 2: fused LSTM weights with GATE-PERMUTED columns.
// Permuted storage row n' (wave w = n'>>5, half = (n'>>4)&1, l15 = n'&15):
//   unit = 8w + 4*half + (l15>>2), gate = l15&3, orig row = gate*64 + unit.
// Wc[dir][n'][0:32)  = W_ih (bf16),  Wc[dir][n'][32:96) = W_hh (bf16).
// biasc[dir][n'] = b[orig] + W_ih[orig]·b_enc  (fp32).
// ---------------------------------------------------------------------------
__global__ void prep_weights(const float* __restrict__ b_enc,
                             const float* __restrict__ W_ih_f,
                             const float* __restrict__ W_hh_f,
                             const float* __restrict__ b_f,
                             const float* __restrict__ W_ih_b,
                             const float* __restrict__ W_hh_b,
                             const float* __restrict__ b_b,
                             __hip_bfloat16* __restrict__ Wc,
                             float* __restrict__ biasc) {
  const int dir = blockIdx.x;
  const int np = threadIdx.x;
  const int w = np >> 5, half = (np >> 4) & 1, l15 = np & 15;
  const int unit = 8 * w + 4 * half + (l15 >> 2);
  const int gate = l15 & 3;
  const int no = gate * 64 + unit;
  const float* W_ih = dir ? W_ih_b : W_ih_f;
  const float* W_hh = dir ? W_hh_b : W_hh_f;
  const float* bv = dir ? b_b : b_f;
  __hip_bfloat16* row = Wc + (size_t)(dir * 256 + np) * 96;
#pragma unroll
  for (int k = 0; k < 32; ++k) row[k] = __float2bfloat16(W_ih[no * 32 + k]);
#pragma unroll
  for (int k = 0; k < 64; ++k) row[32 + k] = __float2bfloat16(W_hh[no * 64 + k]);
  float bb = bv[no];
#pragma unroll
  for (int e = 0; e < 32; ++e) bb += W_ih[no * 32 + e] * b_enc[e];
  biasc[dir * 256 + np] = bb;
}

// ---------------------------------------------------------------------------
// Kernel 3: the recurrence. 128 WGs = 64 batch-tiles(4) x 2 dirs, 512 thr.
// Per step, per wave: gates for 32 permuted cols = A[16,96] @ Wc^T.
//   A rows: batch row lane&3 (rows 4-15 are broadcast copies -> D row r
//   equals batch row r&3 in every quad's reg r).
//   K: [0,32) = x frag from REGISTERS (global prefetch, depth 4);
//      [32,96) = h frag from LDS ping-pong buffer (2 x ds_read_b128).
// Update: lane's gate col g=lane&3; quad handles batch row=quad; the 4 gates
// of a unit sit in one aligned 4-lane group -> quad_perm DPP exchange.
// ONE lgkm-only barrier per step; h(t) written to buf (t+1)&1.
// ---------------------------------------------------------------------------
__global__ __launch_bounds__(512) void lstm_main(
    const __hip_bfloat16* __restrict__ x, const __hip_bfloat16* __restrict__ Wc,
    const float* __restrict__ biasc, float* __restrict__ cfin) {
  __shared__ short Hbuf[2][320];  // [buf][row*80 + unit], units 0-63 used

  const int tid = threadIdx.x, lane = tid & 63, wave = tid >> 6;
  const int quad = lane >> 4, l15 = lane & 15;
  const int g = lane & 3, jj = l15 >> 2;
  const int brow = lane & 3;
  const int dir = (int)blockIdx.x >> 6;
  const int b0 = ((int)blockIdx.x & 63) << 2;

  // loop-invariant weight fragments (B-operand: lane = col n, k = quad*8+j)
  const int n0 = wave * 32 + l15;
  const __hip_bfloat16* wr0 = Wc + (size_t)(dir * 256 + n0) * 96 + quad * 8;
  const __hip_bfloat16* wr1 = wr0 + 16 * 96;
  bfrag8 wf0[3], wf1[3];
#pragma unroll
  for (int kt = 0; kt < 3; ++kt) {
    wf0[kt] = *(const bfrag8*)(wr0 + kt * 32);
    wf1[kt] = *(const bfrag8*)(wr1 + kt * 32);
  }
  const float bias0 = biasc[dir * 256 + n0];
  const float bias1 = biasc[dir * 256 + n0 + 16];

  // activation constants for my gate column (g==2 is the tanh gate)
  const bool isg = (g == 2);
  const float S = isg ? 2.8853900817779268f : -1.4426950408889634f;
  const float Aa = isg ? 1.0f : 0.0f;
  const float Bb = isg ? -2.0f : 1.0f;

  const __hip_bfloat16* xr = x + (size_t)(b0 + brow) * T_LEN * 32 + quad * 8;

  if (tid < 320) Hbuf[0][tid] = 0;  // h0 = 0

  bfrag8 xb[4];
#pragma unroll
  for (int q = 0; q < 4; ++q) {  // prefetch x frags for t = 0..3
    int tp = dir ? (T_LEN - 1 - q) : q;
    xb[q] = *(const bfrag8*)(xr + (size_t)tp * 32);
  }

  float c0 = 0.f, c1 = 0.f;
  const int u0 = 8 * wave + jj, u1 = u0 + 4;  // my units (acc0 / acc1)
  const int hw0 = quad * 80 + u0, hw1 = quad * 80 + u1;
  const int hr = brow * 80 + quad * 8;

  wg_barrier();

#pragma unroll 4
  for (int t = 0; t < T_LEN; ++t) {
    const int cur = t & 1;
    const short* hrow = &Hbuf[cur][hr];
    bfrag8 ah1 = *(const bfrag8*)(hrow);        // h units  0-31 slice
    bfrag8 ah2 = *(const bfrag8*)(hrow + 32);   // h units 32-63 slice
    f32x4 acc0 = {bias0, bias0, bias0, bias0};
    f32x4 acc1 = {bias1, bias1, bias1, bias1};
    acc0 = __builtin_amdgcn_mfma_f32_16x16x32_bf16(xb[t & 3], wf0[0], acc0, 0, 0, 0);
    acc1 = __builtin_amdgcn_mfma_f32_16x16x32_bf16(xb[t & 3], wf1[0], acc1, 0, 0, 0);
    acc0 = __builtin_amdgcn_mfma_f32_16x16x32_bf16(ah1, wf0[1], acc0, 0, 0, 0);
    acc1 = __builtin_amdgcn_mfma_f32_16x16x32_bf16(ah1, wf1[1], acc1, 0, 0, 0);
    acc0 = __builtin_amdgcn_mfma_f32_16x16x32_bf16(ah2, wf0[2], acc0, 0, 0, 0);
    acc1 = __builtin_amdgcn_mfma_f32_16x16x32_bf16(ah2, wf1[2], acc1, 0, 0, 0);
    {  // prefetch x frag for t+4 (stays in flight across the barrier)
      int tn = t + 4;
      if (tn > T_LEN - 1) tn = T_LEN - 1;
      int tp = dir ? (T_LEN - 1 - tn) : tn;
      xb[t & 3] = *(const bfrag8*)(xr + (size_t)tp * 32);
    }
    // my batch row = quad (D row r = batch row r in every quad, reg select)
    float v0 = (quad & 2) ? ((quad & 1) ? acc0[3] : acc0[2])
                          : ((quad & 1) ? acc0[1] : acc0[0]);
    float v1 = (quad & 2) ? ((quad & 1) ? acc1[3] : acc1[2])
                          : ((quad & 1) ? acc1[1] : acc1[0]);
    float a0 = fact(v0, S, Aa, Bb);
    float a1 = fact(v1, S, Aa, Bb);
    // gather the 4 gates of my unit from my 4-lane group (i,f,g,o = lanes 0-3)
    float i0 = qb<0>(a0), f0 = qb<1>(a0), g0 = qb<2>(a0), o0 = qb<3>(a0);
    float i1 = qb<0>(a1), f1 = qb<1>(a1), g1 = qb<2>(a1), o1 = qb<3>(a1);
    c0 = f0 * c0 + i0 * g0;
    c1 = f1 * c1 + i1 * g1;
    float h0 = o0 * ftanh(c0);
    float h1 = o1 * ftanh(c1);
    short* hb = Hbuf[cur ^ 1];
    if (g == 0) *(__hip_bfloat16*)&hb[hw0] = __float2bfloat16(h0);
    if (g == 1) *(__hip_bfloat16*)&hb[hw1] = __float2bfloat16(h1);
    wg_barrier();
  }

  if (g == 0) {  // reference quirk: final CELL state feeds the FC
    float* cf = cfin + (size_t)(dir * 256 + b0 + quad) * 64;
    cf[u0] = c0;
    cf[u1] = c1;
  }
}

// ---------------------------------------------------------------------------
// Kernel 4: out[b,:] = [c_fwd(b) ; c_bwd(b)] @ W_fin^T + b_fin
// ---------------------------------------------------------------------------
__global__ void final_fc(const float* __restrict__ cfin,
                         const float* __restrict__ W_fin,
                         const float* __restrict__ b_fin,
                         float* __restrict__ out) {
  int b = threadIdx.x;  // 256 threads, 1 block
  const float* cf = cfin + (size_t)b * 64;
  const float* cb = cfin + (size_t)(256 + b) * 64;
  float a0 = b_fin[0], a1 = b_fin[1], a2 = b_fin[2];
  for (int u = 0; u < 64; ++u) {
    float vf = cf[u], vb = cb[u];
    a0 += W_fin[0 * 128 + u] * vf + W_fin[0 * 128 + 64 + u] * vb;
    a1 += W_fin[1 * 128 + u] * vf + W_fin[1 * 128 + 64 + u] * vb;
    a2 += W_fin[2 * 128 + u] * vf + W_fin[2 * 128 + 64 + u] * vb;
  }
  out[b * 3 + 0] = a0;
  out[b * 3 + 1] = a1;
  out[b * 3 + 2] = a2;
}

extern "C" void kernel_launch(void* const* d_in, const int* in_sizes, int n_in,
                              void* d_out, int out_size, void* d_ws, size_t ws_size,
                              hipStream_t stream) {
  (void)in_sizes; (void)n_in; (void)out_size; (void)ws_size;
  const float* c      = (const float*)d_in[0];
  const float* W_enc  = (const float*)d_in[1];
  const float* b_enc  = (const float*)d_in[2];
  const float* W_ih_f = (const float*)d_in[3];
  const float* W_hh_f = (const float*)d_in[4];
  const float* b_f    = (const float*)d_in[5];
  const float* W_ih_b = (const float*)d_in[6];
  const float* W_hh_b = (const float*)d_in[7];
  const float* b_b    = (const float*)d_in[8];
  const float* W_fin  = (const float*)d_in[9];
  const float* b_fin  = (const float*)d_in[10];
  float* out = (float*)d_out;

  char* ws = (char*)d_ws;
  __hip_bfloat16* x  = (__hip_bfloat16*)ws;                 // 256*4096*32*2 = 64 MiB
  __hip_bfloat16* Wc = (__hip_bfloat16*)(ws + 67108864);    // 2*256*96*2 = 98304 B
  float* biasc = (float*)(ws + 67108864 + 98304);           // 2048 B
  float* cfin  = (float*)(ws + 67108864 + 98304 + 2048);    // 131072 B

  encoder<<<16384, 256, 0, stream>>>(c, W_enc, x);
  prep_weights<<<2, 256, 0, stream>>>(b_enc, W_ih_f, W_hh_f, b_f,
                                      W_ih_b, W_hh_b, b_b, Wc, biasc);
  lstm_main<<<128, 512, 0, stream>>>(x, Wc, biasc, cfin);
  final_fc<<<1, 256, 0, stream>>>(cfin, W_fin, b_fin, out);
}